// Round 15
// baseline (2965.536 us; speedup 1.0000x reference)
//
#include <hip/hip_runtime.h>

#define SEQ   512
#define BATCH 64
#define DIN   512
#define DH    512
#define KTOT  1024
#define NWG   128
#define NTH   256
#define SLABBYTES 131072        // per parity: 4096 slots x 32 B
#define EPMAGIC 0x5A5A0000u
#define SWEEP_BOUND 262144u     // bounded: break -> absmax fail, never hang

typedef __attribute__((ext_vector_type(8))) short short8;   // 8 x bf16
typedef __attribute__((ext_vector_type(4))) float f32x4;
typedef __attribute__((ext_vector_type(4))) unsigned int u32x4;

__device__ __forceinline__ float tanh_fast(float v) {
    const float e = __expf(2.0f * v);
    return 1.0f - 2.0f / (e + 1.0f);
}
__device__ __forceinline__ unsigned int f2bf(float f) {
    unsigned int u = __float_as_uint(f);
    return (u + 0x7fffu + ((u >> 16) & 1u)) >> 16;
}
__device__ __forceinline__ short8 cvt8(float4 lo, float4 hi) {
    short8 r;
    r[0] = (short)f2bf(lo.x); r[1] = (short)f2bf(lo.y);
    r[2] = (short)f2bf(lo.z); r[3] = (short)f2bf(lo.w);
    r[4] = (short)f2bf(hi.x); r[5] = (short)f2bf(hi.y);
    r[6] = (short)f2bf(hi.z); r[7] = (short)f2bf(hi.w);
    return r;
}

// Persistent MFMA LSTM, round 15: r12 compute path + SELF-CERTIFYING h slots.
// Each producer lane stores ONE 16B {h01, epoch, h23, epoch} (sc0 sc1 ->
// visible at IF$). No drain, no tags, no flags, no memset. Consumers sweep
// sc1 dwordx4 loads and retry until all 32 epochs == magic|(t-1) - detection
// and data share one RTT. Depth-2 ping-pong; WAR-safe by the r5 argument
// (the epoch-store certifies this wave's previous reads retired); the
// sweep's vmcnt(0) each step orders same-address stores across t/t+2.
// k-tiles consumed in two static halves (half-0 MFMA overlaps half-1 arrival).
__global__ __launch_bounds__(NTH, 1)
void lstm_mfma(const float* __restrict__ x,
               const float* __restrict__ Wf, const float* __restrict__ bfp,
               const float* __restrict__ Wi, const float* __restrict__ bip,
               const float* __restrict__ Wg, const float* __restrict__ bgp,
               const float* __restrict__ Wo, const float* __restrict__ bop,
               float* __restrict__ out,
               char* __restrict__ slab)
{
    const int tid = threadIdx.x;
    const int l   = tid & 63;
    const int mt  = tid >> 6;              // wave = M-tile (batches mt*16..+15)
    const int wg  = blockIdx.x;
    const int j0  = wg * 4;

    const int n    = l & 15;               // weight row (gate*4 + jc)
    const int khi  = l >> 4;               // k-group; in C: gate index
    const bool isg = (khi == 2);

    // ---- weights: 32 fragments in VGPRs (r12 mapping) ----------------------
    const float* Wn = (n < 8) ? ((n < 4) ? Wf : Wi) : ((n < 12) ? Wg : Wo);
    const float* wrow = Wn + (size_t)(j0 + (n & 3)) * KTOT + khi * 8;
    short8 Bfr[32];
    #pragma unroll
    for (int kt = 0; kt < 32; ++kt) {
        Bfr[kt] = cvt8(*(const float4*)(wrow + kt * 32),
                       *(const float4*)(wrow + kt * 32 + 4));
    }
    const float* bptr = (khi == 0) ? bfp : (khi == 1) ? bip : (khi == 2) ? bgp : bop;
    const float4 bias4 = *(const float4*)(bptr + j0);

    float cst0 = 0.f, cst1 = 0.f, cst2 = 0.f, cst3 = 0.f;
    float* const hx_out = out + (size_t)SEQ * BATCH * DH;
    float* const cx_out = hx_out + (size_t)BATCH * DH;

    // producer slot: ((mt*16 + kth)*64 + (lane_f_base|l))*32 + (wg&1)*16
    const int kth         = wg >> 3;
    const int lane_f_base = ((wg & 7) >> 1) << 4;
    const size_t prod_off = ((((size_t)(mt * 16 + kth) * 64)
                             + (size_t)(lane_f_base | l)) << 5)
                          + (size_t)(wg & 1) * 16;

    const float* xrow_base = x + (size_t)(mt * 16 + n) * DIN + khi * 8;

    bool dead = false;

    for (int t = 0; t < SEQ && !dead; ++t) {
        f32x4 acc_a = {0.f, 0.f, 0.f, 0.f};
        f32x4 acc_b = {0.f, 0.f, 0.f, 0.f};

        // ---------- phase X: x[t] contribution (dependency-free) -----------
        {
            const float* xr = xrow_base + (size_t)t * BATCH * DIN;
            #pragma unroll
            for (int kt = 0; kt < 16; kt += 2) {
                const short8 a0 = cvt8(*(const float4*)(xr + kt * 32),
                                       *(const float4*)(xr + kt * 32 + 4));
                const short8 a1 = cvt8(*(const float4*)(xr + (kt + 1) * 32),
                                       *(const float4*)(xr + (kt + 1) * 32 + 4));
                acc_a = __builtin_amdgcn_mfma_f32_16x16x32_bf16(Bfr[kt], a0, acc_a, 0, 0, 0);
                acc_b = __builtin_amdgcn_mfma_f32_16x16x32_bf16(Bfr[kt + 1], a1, acc_b, 0, 0, 0);
            }
        }

        if (t > 0) {
            const unsigned int e = EPMAGIC | (unsigned int)(t - 1);
            const char* hb = slab + (size_t)((t & 1) ^ 1) * SLABBYTES
                           + (((size_t)(mt * 16) * 64 + l) << 5);

            #pragma unroll
            for (int hf = 0; hf < 2; ++hf) {
                const char* b0 = hb + hf * 16384;   // k-tiles hf*8 .. +7
                const char* b1 = b0 + 4096;
                const char* b2 = b0 + 8192;
                const char* b3 = b0 + 12288;
                u32x4 q0, q1, q2, q3, q4, q5, q6, q7;
                u32x4 q8, q9, qA, qB, qC, qD, qE, qF;
                for (unsigned int it = 0;; ++it) {
                    asm volatile(
                        "global_load_dwordx4 %0,  %16, off sc0 sc1\n\t"
                        "global_load_dwordx4 %1,  %16, off offset:16 sc0 sc1\n\t"
                        "global_load_dwordx4 %2,  %16, off offset:2048 sc0 sc1\n\t"
                        "global_load_dwordx4 %3,  %16, off offset:2064 sc0 sc1\n\t"
                        "global_load_dwordx4 %4,  %17, off sc0 sc1\n\t"
                        "global_load_dwordx4 %5,  %17, off offset:16 sc0 sc1\n\t"
                        "global_load_dwordx4 %6,  %17, off offset:2048 sc0 sc1\n\t"
                        "global_load_dwordx4 %7,  %17, off offset:2064 sc0 sc1\n\t"
                        "global_load_dwordx4 %8,  %18, off sc0 sc1\n\t"
                        "global_load_dwordx4 %9,  %18, off offset:16 sc0 sc1\n\t"
                        "global_load_dwordx4 %10, %18, off offset:2048 sc0 sc1\n\t"
                        "global_load_dwordx4 %11, %18, off offset:2064 sc0 sc1\n\t"
                        "global_load_dwordx4 %12, %19, off sc0 sc1\n\t"
                        "global_load_dwordx4 %13, %19, off offset:16 sc0 sc1\n\t"
                        "global_load_dwordx4 %14, %19, off offset:2048 sc0 sc1\n\t"
                        "global_load_dwordx4 %15, %19, off offset:2064 sc0 sc1\n\t"
                        "s_waitcnt vmcnt(0)"
                        : "=&v"(q0), "=&v"(q1), "=&v"(q2), "=&v"(q3),
                          "=&v"(q4), "=&v"(q5), "=&v"(q6), "=&v"(q7),
                          "=&v"(q8), "=&v"(q9), "=&v"(qA), "=&v"(qB),
                          "=&v"(qC), "=&v"(qD), "=&v"(qE), "=&v"(qF)
                        : "v"(b0), "v"(b1), "v"(b2), "v"(b3)
                        : "memory");
                    const unsigned int bad =
                        (q0[1]^e)|(q0[3]^e)|(q1[1]^e)|(q1[3]^e)|
                        (q2[1]^e)|(q2[3]^e)|(q3[1]^e)|(q3[3]^e)|
                        (q4[1]^e)|(q4[3]^e)|(q5[1]^e)|(q5[3]^e)|
                        (q6[1]^e)|(q6[3]^e)|(q7[1]^e)|(q7[3]^e)|
                        (q8[1]^e)|(q8[3]^e)|(q9[1]^e)|(q9[3]^e)|
                        (qA[1]^e)|(qA[3]^e)|(qB[1]^e)|(qB[3]^e)|
                        (qC[1]^e)|(qC[3]^e)|(qD[1]^e)|(qD[3]^e)|
                        (qE[1]^e)|(qE[3]^e)|(qF[1]^e)|(qF[3]^e);
                    if (__all(bad == 0u)) break;
                    if (it >= SWEEP_BOUND) { dead = true; break; }
                    __builtin_amdgcn_s_sleep(1);
                }
                if (dead) break;

                // 8 MFMAs: k-tile kt uses q[2k], q[2k+1]
#define DOKT(KT, QA, QB) { u32x4 fv; fv[0] = QA[0]; fv[1] = QA[2];            \
    fv[2] = QB[0]; fv[3] = QB[2];                                             \
    union { u32x4 u; short8 v; } Uu; Uu.u = fv;                               \
    if ((KT) & 1) acc_b = __builtin_amdgcn_mfma_f32_16x16x32_bf16(            \
                              Bfr[16 + (KT)], Uu.v, acc_b, 0, 0, 0);          \
    else          acc_a = __builtin_amdgcn_mfma_f32_16x16x32_bf16(            \
                              Bfr[16 + (KT)], Uu.v, acc_a, 0, 0, 0); }
                if (hf == 0) {
                    DOKT(0, q0, q1)  DOKT(1, q2, q3)  DOKT(2, q4, q5)
                    DOKT(3, q6, q7)  DOKT(4, q8, q9)  DOKT(5, qA, qB)
                    DOKT(6, qC, qD)  DOKT(7, qE, qF)
                } else {
                    DOKT(8, q0, q1)  DOKT(9, q2, q3)  DOKT(10, q4, q5)
                    DOKT(11, q6, q7) DOKT(12, q8, q9) DOKT(13, qA, qB)
                    DOKT(14, qC, qD) DOKT(15, qE, qF)
                }
#undef DOKT
            }
            if (dead) break;
        }

        // ---------- epilogue: gates on ALL lanes, gather, update -----------
        float aq0, aq1, aq2, aq3;
        {
            const float m = isg ? 2.0f : 1.0f;
            const float p0 = acc_a[0] + acc_b[0] + bias4.x;
            const float p1 = acc_a[1] + acc_b[1] + bias4.y;
            const float p2 = acc_a[2] + acc_b[2] + bias4.z;
            const float p3 = acc_a[3] + acc_b[3] + bias4.w;
            const float y0 = 1.0f / (1.0f + __expf(-m * p0));
            const float y1 = 1.0f / (1.0f + __expf(-m * p1));
            const float y2 = 1.0f / (1.0f + __expf(-m * p2));
            const float y3 = 1.0f / (1.0f + __expf(-m * p3));
            aq0 = isg ? 2.0f * y0 - 1.0f : y0;
            aq1 = isg ? 2.0f * y1 - 1.0f : y1;
            aq2 = isg ? 2.0f * y2 - 1.0f : y2;
            aq3 = isg ? 2.0f * y3 - 1.0f : y3;
        }
        const float i0 = __shfl_xor(aq0, 16), g0 = __shfl_xor(aq0, 32), o0 = __shfl_xor(aq0, 48);
        const float i1 = __shfl_xor(aq1, 16), g1 = __shfl_xor(aq1, 32), o1 = __shfl_xor(aq1, 48);
        const float i2 = __shfl_xor(aq2, 16), g2 = __shfl_xor(aq2, 32), o2 = __shfl_xor(aq2, 48);
        const float i3 = __shfl_xor(aq3, 16), g3 = __shfl_xor(aq3, 32), o3 = __shfl_xor(aq3, 48);

        const bool active = (l < 16);          // lane l = batch mt*16+l
        float hq0 = 0.f, hq1 = 0.f, hq2 = 0.f, hq3 = 0.f;

        if (active) {
            cst0 = fmaf(aq0, cst0, i0 * g0); hq0 = o0 * tanh_fast(cst0);
            cst1 = fmaf(aq1, cst1, i1 * g1); hq1 = o1 * tanh_fast(cst1);
            cst2 = fmaf(aq2, cst2, i2 * g2); hq2 = o2 * tanh_fast(cst2);
            cst3 = fmaf(aq3, cst3, i3 * g3); hq3 = o3 * tanh_fast(cst3);

            if (t < SEQ - 1) {
                // ONE self-certifying 16B store: {h01, epoch, h23, epoch}
                u32x4 pkt;
                pkt[0] = f2bf(hq0) | (f2bf(hq1) << 16);
                pkt[1] = EPMAGIC | (unsigned int)t;
                pkt[2] = f2bf(hq2) | (f2bf(hq3) << 16);
                pkt[3] = EPMAGIC | (unsigned int)t;
                char* hp_w = slab + (size_t)(t & 1) * SLABBYTES + prod_off;
                asm volatile("global_store_dwordx4 %0, %1, off sc0 sc1"
                             :: "v"(hp_w), "v"(pkt) : "memory");
            }

            // out writes off the critical path
            const int b = mt * 16 + l;
            const float4 ov = make_float4(hq0, hq1, hq2, hq3);
            *(float4*)(out + ((size_t)t * BATCH + b) * DH + j0) = ov;
            if (t == SEQ - 1) {
                *(float4*)(hx_out + (size_t)b * DH + j0) = ov;
                *(float4*)(cx_out + (size_t)b * DH + j0) =
                    make_float4(cst0, cst1, cst2, cst3);
            }
        }
    }
}

extern "C" void kernel_launch(void* const* d_in, const int* in_sizes, int n_in,
                              void* d_out, int out_size, void* d_ws, size_t ws_size,
                              hipStream_t stream)
{
    const float* x  = (const float*)d_in[0];
    const float* Wf = (const float*)d_in[1];
    const float* bf = (const float*)d_in[2];
    const float* Wi = (const float*)d_in[3];
    const float* bi = (const float*)d_in[4];
    const float* Wg = (const float*)d_in[5];
    const float* bg = (const float*)d_in[6];
    const float* Wo = (const float*)d_in[7];
    const float* bo = (const float*)d_in[8];
    float* out = (float*)d_out;

    // No ws init needed: slots are self-certifying (epoch magic|t). Stale
    // slots from a previous call hold epoch magic|(t+510) (never == expected
    // within a call) or, on replays, byte-identical h values (deterministic).
    lstm_mfma<<<NWG, NTH, 0, stream>>>(x, Wf, bf, Wi, bi, Wg, bg, Wo, bo,
                                       out, (char*)d_ws);
}

// Round 16
// 2149.381 us; speedup vs baseline: 1.3797x; 1.3797x over previous
//
#include <hip/hip_runtime.h>

#define SEQ   512
#define BATCH 64
#define DIN   512
#define DH    512
#define KTOT  1024
#define NWG   128
#define NTH   256
#define HBUF_BYTES 65536   // one h step: 64 tiles * 64 lanes * 16 B

// ws layout (bytes):
//   [0, 2K)            PACKED per-(mt,wg) tags: (mt*128 + wg) * 4B
//                      (poll sweep touches 4 lines, not 128 — r16 change)
//   [64K, ...)         MODE0: ping-pong h (2 x 64 KB)
//                      MODE1/2: per-step virgin h buffers (511 x 64 KB)
//   [33M, 33M+32M)     MODE2: x pre-converted to bf16 fragment layout
#define FLAGS_BYTES 65536
#define HBASE_OFF   65536
#define XBF_OFF     (HBASE_OFF + 512 * HBUF_BYTES)        // ~33.6 MB
#define XBF_BYTES   ((size_t)SEQ * 4 * 16 * 1024)         // 32 MB
#define WS_MODE1    ((size_t)HBASE_OFF + 511 * HBUF_BYTES)
#define WS_MODE2    ((size_t)XBF_OFF + XBF_BYTES)
#define FLAG_STRIDE 1    // uints (4 B) — packed; was 32 (128 B) in r12

typedef __attribute__((ext_vector_type(8))) short short8;   // 8 x bf16
typedef __attribute__((ext_vector_type(4))) float f32x4;

__device__ __forceinline__ float tanh_fast(float v) {
    const float e = __expf(2.0f * v);
    return 1.0f - 2.0f / (e + 1.0f);
}

// fp32 -> bf16 RNE (finite inputs)
__device__ __forceinline__ unsigned int f2bf(float f) {
    unsigned int u = __float_as_uint(f);
    return (u + 0x7fffu + ((u >> 16) & 1u)) >> 16;
}

__device__ __forceinline__ short8 cvt8(float4 lo, float4 hi) {
    short8 r;
    r[0] = (short)f2bf(lo.x); r[1] = (short)f2bf(lo.y);
    r[2] = (short)f2bf(lo.z); r[3] = (short)f2bf(lo.w);
    r[4] = (short)f2bf(hi.x); r[5] = (short)f2bf(hi.y);
    r[6] = (short)f2bf(hi.z); r[7] = (short)f2bf(hi.w);
    return r;
}

__device__ __forceinline__ unsigned int ld_flag(const unsigned int* p) {
    return __hip_atomic_load(p, __ATOMIC_RELAXED, __HIP_MEMORY_SCOPE_AGENT);
}
__device__ __forceinline__ void st_flag(unsigned int* p, unsigned int v) {
    __hip_atomic_store(p, v, __ATOMIC_RELAXED, __HIP_MEMORY_SCOPE_AGENT);
}
__device__ __forceinline__ unsigned long long ld_h_sc1(const unsigned long long* p) {
    return __hip_atomic_load(p, __ATOMIC_RELAXED, __HIP_MEMORY_SCOPE_AGENT);
}
__device__ __forceinline__ void st_h(unsigned long long* p, unsigned long long v) {
    __hip_atomic_store(p, v, __ATOMIC_RELAXED, __HIP_MEMORY_SCOPE_AGENT);
}

// Pre-pass: x fp32 -> bf16 in MFMA fragment layout.
// idx = ((t*4 + mt)*16 + kt)*64 + l holds x[t][mt*16+(l&15)][kt*32+(l>>4)*8 ..+8]
__global__ __launch_bounds__(256)
void xconv(const float* __restrict__ x, unsigned short* __restrict__ xbf)
{
    const int gid = blockIdx.x * 256 + threadIdx.x;
    const int l   = gid & 63;
    const int kt  = (gid >> 6) & 15;
    const int mtt = (gid >> 10) & 3;
    const int t   = gid >> 12;
    const float* src = x + ((size_t)t * BATCH + mtt * 16 + (l & 15)) * DIN
                         + kt * 32 + (l >> 4) * 8;
    *(short8*)(xbf + (size_t)gid * 8) =
        cvt8(*(const float4*)src, *(const float4*)(src + 4));
}

// Persistent MFMA LSTM, round 16: r12 with PACKED tags (4B stride).
// One poll iteration touches 4 cachelines instead of 128 (32x less IF$
// line traffic). Producer: one 4B sc1 store (byte-disjoint within line,
// no RMW, once per step). Everything else identical to r12: barrier-free
// per-wave tags, virgin per-step h buffers with cached loads, operand-
// swapped MFMA, all-lane gate transcendentals.
// MODE 0: ping-pong h, sc1 loads  / MODE 1: virgin buffers, cached loads /
// MODE 2: MODE1 + pre-converted bf16 x.
template <int MODE>
__global__ __launch_bounds__(NTH, 1)
void lstm_mfma(const float* __restrict__ x,
               const unsigned short* __restrict__ xbf,
               const float* __restrict__ Wf, const float* __restrict__ bfp,
               const float* __restrict__ Wi, const float* __restrict__ bip,
               const float* __restrict__ Wg, const float* __restrict__ bgp,
               const float* __restrict__ Wo, const float* __restrict__ bop,
               float* __restrict__ out,
               unsigned int* __restrict__ ws_u32)
{
    const int tid = threadIdx.x;
    const int l   = tid & 63;
    const int mt  = tid >> 6;              // wave = M-tile (batches mt*16..+15)
    const int wg  = blockIdx.x;
    const int j0  = wg * 4;

    const int n    = l & 15;               // weight row (gate*4 + jc)
    const int khi  = l >> 4;               // k-group; in C: gate index
    const bool isg = (khi == 2);           // this lane's C-rows are gate 'g'

    unsigned int* const flags = ws_u32;    // (mt*128 + wg) * FLAG_STRIDE
    char* const hbase = (char*)ws_u32 + HBASE_OFF;

    // ---- load the 32 weight fragments (bf16) into VGPRs, once --------------
    const float* Wn = (n < 8) ? ((n < 4) ? Wf : Wi) : ((n < 12) ? Wg : Wo);
    const float* wrow = Wn + (size_t)(j0 + (n & 3)) * KTOT + khi * 8;
    short8 Bfr[32];
    #pragma unroll
    for (int kt = 0; kt < 32; ++kt) {
        Bfr[kt] = cvt8(*(const float4*)(wrow + kt * 32),
                       *(const float4*)(wrow + kt * 32 + 4));
    }
    // bias: this lane's C-gate (khi) at columns j0..j0+3
    const float* bptr = (khi == 0) ? bfp : (khi == 1) ? bip : (khi == 2) ? bgp : bop;
    const float4 bias4 = *(const float4*)(bptr + j0);

    // c-state: lanes l<16 hold c[b = mt*16+l][j0+q], q = 0..3
    float cst0 = 0.f, cst1 = 0.f, cst2 = 0.f, cst3 = 0.f;

    float* const hx_out = out + (size_t)SEQ * BATCH * DH;
    float* const cx_out = hx_out + (size_t)BATCH * DH;

    // producer-side h-fragment coordinates (constant over t)
    const int kth         = wg >> 3;                    // h k-tile 0..15
    const int lane_f_base = ((wg & 7) >> 1) << 4;       // hi<<4
    const int half8       = (wg & 1) * 8;               // byte offset of j-quad

    // self-poll pointers: the 128 same-mt producer tags (packed, 4 lines)
    const unsigned int* const f0p = flags + ((size_t)mt * 128 + l) * FLAG_STRIDE;
    const unsigned int* const f1p = f0p + (size_t)64 * FLAG_STRIDE;
    unsigned int* const my_flag = flags + ((size_t)mt * 128 + wg) * FLAG_STRIDE;

    const float*  xrow_base = x + (size_t)(mt * 16 + (l & 15)) * DIN + khi * 8;
    const short8* xbf_base  = (const short8*)xbf + (size_t)mt * 16 * 64 + l;

    for (int t = 0; t < SEQ; ++t) {
        f32x4 acc_a = {0.f, 0.f, 0.f, 0.f};
        f32x4 acc_b = {0.f, 0.f, 0.f, 0.f};

        // ---------- phase X: x[t] contribution (dependency-free) -----------
        if (MODE == 2) {
            const short8* xp = xbf_base + (size_t)t * 4096;   // (t*4+mt)*16*64+l
            #pragma unroll
            for (int kt = 0; kt < 16; kt += 2) {
                acc_a = __builtin_amdgcn_mfma_f32_16x16x32_bf16(Bfr[kt], xp[kt * 64],
                                                                acc_a, 0, 0, 0);
                acc_b = __builtin_amdgcn_mfma_f32_16x16x32_bf16(Bfr[kt + 1], xp[(kt + 1) * 64],
                                                                acc_b, 0, 0, 0);
            }
        } else {
            const float* xr = xrow_base + (size_t)t * BATCH * DIN;
            #pragma unroll
            for (int kt = 0; kt < 16; kt += 2) {
                const short8 a0 = cvt8(*(const float4*)(xr + kt * 32),
                                       *(const float4*)(xr + kt * 32 + 4));
                const short8 a1 = cvt8(*(const float4*)(xr + (kt + 1) * 32),
                                       *(const float4*)(xr + (kt + 1) * 32 + 4));
                acc_a = __builtin_amdgcn_mfma_f32_16x16x32_bf16(Bfr[kt], a0, acc_a, 0, 0, 0);
                acc_b = __builtin_amdgcn_mfma_f32_16x16x32_bf16(Bfr[kt + 1], a1, acc_b, 0, 0, 0);
            }
        }

        if (t > 0) {
            // ------ per-wave dependency wait: 128 same-mt tags >= t --------
            const unsigned int target = (unsigned int)t;
            for (;;) {
                const unsigned int fa = ld_flag(f0p);
                const unsigned int fb = ld_flag(f1p);
                if (__all(fa >= target && fb >= target)) break;
                __builtin_amdgcn_s_sleep(1);
            }
            asm volatile("" ::: "memory");   // keep h-loads after the poll

            // ---------- phase H: h[t-1] -------------------------------------
            if (MODE == 0) {
                const unsigned long long* hp =
                    (const unsigned long long*)(hbase + ((t & 1) ^ 1) * HBUF_BYTES)
                    + ((size_t)(mt * 16) * 64 + l) * 2;
                #pragma unroll
                for (int kt = 0; kt < 16; kt += 2) {
                    union { unsigned long long u[2]; short8 v; } U0, U1;
                    U0.u[0] = ld_h_sc1(hp + kt * 128);
                    U0.u[1] = ld_h_sc1(hp + kt * 128 + 1);
                    U1.u[0] = ld_h_sc1(hp + (kt + 1) * 128);
                    U1.u[1] = ld_h_sc1(hp + (kt + 1) * 128 + 1);
                    acc_a = __builtin_amdgcn_mfma_f32_16x16x32_bf16(Bfr[16 + kt], U0.v,
                                                                    acc_a, 0, 0, 0);
                    acc_b = __builtin_amdgcn_mfma_f32_16x16x32_bf16(Bfr[17 + kt], U1.v,
                                                                    acc_b, 0, 0, 0);
                }
            } else {
                // virgin per-step buffer: plain CACHED loads (L2-shared/XCD)
                const uint4* hp = (const uint4*)(hbase + (size_t)(t - 1) * HBUF_BYTES)
                                  + ((size_t)(mt * 16) * 64 + l);
                uint4 hv[16];
                #pragma unroll
                for (int kt = 0; kt < 16; ++kt) hv[kt] = hp[kt * 64];
                #pragma unroll
                for (int kt = 0; kt < 16; kt += 2) {
                    union { uint4 u; short8 v; } U0, U1;
                    U0.u = hv[kt]; U1.u = hv[kt + 1];
                    acc_a = __builtin_amdgcn_mfma_f32_16x16x32_bf16(Bfr[16 + kt], U0.v,
                                                                    acc_a, 0, 0, 0);
                    acc_b = __builtin_amdgcn_mfma_f32_16x16x32_bf16(Bfr[17 + kt], U1.v,
                                                                    acc_b, 0, 0, 0);
                }
            }
        }

        // ---------- epilogue: gates on ALL lanes, gather, update -----------
        // C (swapped): col (l&15) = batch, row m = khi*4+q -> gate=khi, jc=q.
        float aq0, aq1, aq2, aq3;
        {
            const float m = isg ? 2.0f : 1.0f;
            const float p0 = acc_a[0] + acc_b[0] + bias4.x;
            const float p1 = acc_a[1] + acc_b[1] + bias4.y;
            const float p2 = acc_a[2] + acc_b[2] + bias4.z;
            const float p3 = acc_a[3] + acc_b[3] + bias4.w;
            const float y0 = 1.0f / (1.0f + __expf(-m * p0));
            const float y1 = 1.0f / (1.0f + __expf(-m * p1));
            const float y2 = 1.0f / (1.0f + __expf(-m * p2));
            const float y3 = 1.0f / (1.0f + __expf(-m * p3));
            aq0 = isg ? 2.0f * y0 - 1.0f : y0;
            aq1 = isg ? 2.0f * y1 - 1.0f : y1;
            aq2 = isg ? 2.0f * y2 - 1.0f : y2;
            aq3 = isg ? 2.0f * y3 - 1.0f : y3;
        }
        const float i0 = __shfl_xor(aq0, 16), g0 = __shfl_xor(aq0, 32), o0 = __shfl_xor(aq0, 48);
        const float i1 = __shfl_xor(aq1, 16), g1 = __shfl_xor(aq1, 32), o1 = __shfl_xor(aq1, 48);
        const float i2 = __shfl_xor(aq2, 16), g2 = __shfl_xor(aq2, 32), o2 = __shfl_xor(aq2, 48);
        const float i3 = __shfl_xor(aq3, 16), g3 = __shfl_xor(aq3, 32), o3 = __shfl_xor(aq3, 48);

        const bool active = (l < 16);            // lane l = batch mt*16+l
        float hq0 = 0.f, hq1 = 0.f, hq2 = 0.f, hq3 = 0.f;

        if (active) {
            cst0 = fmaf(aq0, cst0, i0 * g0); hq0 = o0 * tanh_fast(cst0);
            cst1 = fmaf(aq1, cst1, i1 * g1); hq1 = o1 * tanh_fast(cst1);
            cst2 = fmaf(aq2, cst2, i2 * g2); hq2 = o2 * tanh_fast(cst2);
            cst3 = fmaf(aq3, cst3, i3 * g3); hq3 = o3 * tanh_fast(cst3);

            if (t < SEQ - 1) {
                // direct 8B h-pack: this lane's 4 jc-values of batch mt*16+l
                const unsigned long long pk =
                    (unsigned long long)(f2bf(hq0) | (f2bf(hq1) << 16))
                    | ((unsigned long long)(f2bf(hq2) | (f2bf(hq3) << 16)) << 32);
                char* const wb = (MODE == 0) ? hbase + (t & 1) * HBUF_BYTES
                                             : hbase + (size_t)t * HBUF_BYTES;
                unsigned long long* hp_w = (unsigned long long*)
                    (wb + (((size_t)(mt * 16 + kth) * 64
                            + (lane_f_base | l)) << 4) + half8);
                st_h(hp_w, pk);     // sc1 write-through: visible at IF$
            }
        }

        if (t < SEQ - 1) {
            // this wave's h-stores drained, then publish this wave's tag
            asm volatile("s_waitcnt vmcnt(0)" ::: "memory");
            if (l == 0) st_flag(my_flag, (unsigned int)(t + 1));
        }

        if (active) {      // out writes off the critical path
            const int b = mt * 16 + l;
            const float4 ov = make_float4(hq0, hq1, hq2, hq3);
            *(float4*)(out + ((size_t)t * BATCH + b) * DH + j0) = ov;
            if (t == SEQ - 1) {
                *(float4*)(hx_out + (size_t)b * DH + j0) = ov;
                *(float4*)(cx_out + (size_t)b * DH + j0) =
                    make_float4(cst0, cst1, cst2, cst3);
            }
        }
    }
}

extern "C" void kernel_launch(void* const* d_in, const int* in_sizes, int n_in,
                              void* d_out, int out_size, void* d_ws, size_t ws_size,
                              hipStream_t stream)
{
    const float* x  = (const float*)d_in[0];
    const float* Wf = (const float*)d_in[1];
    const float* bf = (const float*)d_in[2];
    const float* Wi = (const float*)d_in[3];
    const float* bi = (const float*)d_in[4];
    const float* Wg = (const float*)d_in[5];
    const float* bg = (const float*)d_in[6];
    const float* Wo = (const float*)d_in[7];
    const float* bo = (const float*)d_in[8];
    float* out = (float*)d_out;

    // Tag flags must be 0 every call (monotone within a call; ws poisoned 0xAA
    // once, never re-poisoned). h buffers: written-before-read each call;
    // across graph replays values are identical, so cached copies stay valid.
    hipMemsetAsync(d_ws, 0, FLAGS_BYTES, stream);

    unsigned int* wsp = (unsigned int*)d_ws;
    if (ws_size >= WS_MODE2) {
        unsigned short* xbf = (unsigned short*)((char*)d_ws + XBF_OFF);
        xconv<<<SEQ * 4 * 16 * 64 / 256, 256, 0, stream>>>(x, xbf);
        lstm_mfma<2><<<NWG, NTH, 0, stream>>>(x, xbf, Wf, bf, Wi, bi,
                                              Wg, bg, Wo, bo, out, wsp);
    } else if (ws_size >= WS_MODE1) {
        lstm_mfma<1><<<NWG, NTH, 0, stream>>>(x, nullptr, Wf, bf, Wi, bi,
                                              Wg, bg, Wo, bo, out, wsp);
    } else {
        lstm_mfma<0><<<NWG, NTH, 0, stream>>>(x, nullptr, Wf, bf, Wi, bi,
                                              Wg, bg, Wo, bo, out, wsp);
    }
}